// Round 10
// baseline (121.748 us; speedup 1.0000x reference)
//
#include <hip/hip_runtime.h>

constexpr int N_NODES = 10000;
constexpr int N_EDGES = 320000;
constexpr int IN_CH   = 128;
constexpr int HID     = 64;
constexpr int HEADS   = 4;
constexpr int OUT_CH  = 64;
constexpr int F1      = HEADS * HID;   // 256
constexpr int CAP     = 128;           // max in-degree capacity (deg~Poisson(32))
constexpr float NEG_SLOPE = 0.2f;
constexpr int GEMM_BLOCKS = (N_NODES + 31) / 32;   // 313
constexpr int HALF_E = N_EDGES / 2;                // 160000

// ---------------- init: zero cnt + compute de ----------------

__global__ void k_init(int* __restrict__ cnt,
                       const float* __restrict__ We1, const float* __restrict__ ae1,
                       const float* __restrict__ We2, const float* __restrict__ ae2,
                       float* __restrict__ de) {
    int bid = blockIdx.x;
    if (bid < 40) {
        int i = bid * 256 + threadIdx.x;
        if (i < N_NODES) cnt[i] = 0;
        return;
    }
    int t = threadIdx.x;
    if (t < HEADS) {
        float s = 0.f;
        for (int c = 0; c < HID; ++c) s = fmaf(We1[t * HID + c], ae1[t * HID + c], s);
        de[t] = s;
    } else if (t == HEADS) {
        float s = 0.f;
        for (int c = 0; c < OUT_CH; ++c) s = fmaf(We2[c], ae2[c], s);
        de[HEADS] = s;
    }
}

// ---------------- fill: padded buckets, 8B scatter only, 2 edges/thread ---------

__global__ void k_fill(const int* __restrict__ src, const int* __restrict__ dst,
                       const float* __restrict__ ew,
                       int* __restrict__ cnt, int2* __restrict__ sw_pad) {
    int e0 = blockIdx.x * 256 + threadIdx.x;   // covers [0, HALF_E)
    int e1 = e0 + HALF_E;
    int s0 = src[e0], d0 = dst[e0];
    int s1 = src[e1], d1 = dst[e1];
    float w0 = ew[e0], w1 = ew[e1];
    int p0 = atomicAdd(&cnt[d0], 1);
    int p1 = atomicAdd(&cnt[d1], 1);
    if (p0 < CAP) sw_pad[(size_t)d0 * CAP + p0] = make_int2(s0, __float_as_int(w0));
    if (p1 < CAP) sw_pad[(size_t)d1 * CAP + p1] = make_int2(s1, __float_as_int(w1));
}

// ---------------- GEMM1 + fused src/dst dots; all outputs head-major ------------

__global__ __launch_bounds__(256) void k_gemm1(const float* __restrict__ x,
                                               const float* __restrict__ W,
                                               const float* __restrict__ a_src,
                                               const float* __restrict__ a_dst,
                                               float* __restrict__ xh1T,
                                               float* __restrict__ alsT,
                                               float* __restrict__ aldT) {
    __shared__ float xs[32 * IN_CH];                       // 16 KB
    int tid = threadIdx.x;
    int row0 = blockIdx.x * 32;
    int nrows = N_NODES - row0; if (nrows > 32) nrows = 32;
    float4* xs4 = (float4*)xs;
    const float4* xg = (const float4*)(x + (size_t)row0 * IN_CH);
    #pragma unroll
    for (int j = 0; j < 4; ++j) {
        int idx = tid + j * 256;
        if ((idx >> 5) < nrows) xs4[idx] = xg[idx];
    }
    __syncthreads();
    int wv = tid >> 6;
    int lane = tid & 63;
    int col = lane * 4;
    int h = lane >> 4;
    int c = (lane & 15) * 4;
    float acc[8][4];
    #pragma unroll
    for (int m = 0; m < 8; ++m)
        #pragma unroll
        for (int j = 0; j < 4; ++j) acc[m][j] = 0.f;

    for (int k = 0; k < IN_CH; k += 4) {
        float4 w0 = *(const float4*)(W + (size_t)(k + 0) * F1 + col);
        float4 w1 = *(const float4*)(W + (size_t)(k + 1) * F1 + col);
        float4 w2 = *(const float4*)(W + (size_t)(k + 2) * F1 + col);
        float4 w3 = *(const float4*)(W + (size_t)(k + 3) * F1 + col);
        #pragma unroll
        for (int m = 0; m < 8; ++m) {
            float4 xv = *(const float4*)(xs + (wv * 8 + m) * IN_CH + k);
            acc[m][0] = fmaf(xv.x, w0.x, fmaf(xv.y, w1.x, fmaf(xv.z, w2.x, fmaf(xv.w, w3.x, acc[m][0]))));
            acc[m][1] = fmaf(xv.x, w0.y, fmaf(xv.y, w1.y, fmaf(xv.z, w2.y, fmaf(xv.w, w3.y, acc[m][1]))));
            acc[m][2] = fmaf(xv.x, w0.z, fmaf(xv.y, w1.z, fmaf(xv.z, w2.z, fmaf(xv.w, w3.z, acc[m][2]))));
            acc[m][3] = fmaf(xv.x, w0.w, fmaf(xv.y, w1.w, fmaf(xv.z, w2.w, fmaf(xv.w, w3.w, acc[m][3]))));
        }
    }
    float4 asv = *(const float4*)(a_src + h * HID + c);
    float4 adv = *(const float4*)(a_dst + h * HID + c);
    #pragma unroll
    for (int m = 0; m < 8; ++m) {
        int row = wv * 8 + m;
        if (row < nrows)
            *(float4*)(xh1T + ((size_t)h * N_NODES + row0 + row) * HID + c) = *(float4*)acc[m];
        float s = acc[m][0] * asv.x + acc[m][1] * asv.y + acc[m][2] * asv.z + acc[m][3] * asv.w;
        float d = acc[m][0] * adv.x + acc[m][1] * adv.y + acc[m][2] * adv.z + acc[m][3] * adv.w;
        #pragma unroll
        for (int off = 1; off < 16; off <<= 1) {
            s += __shfl_xor(s, off, 64);
            d += __shfl_xor(d, off, 64);
        }
        if ((lane & 15) == 0 && row < nrows) {
            alsT[(size_t)h * N_NODES + row0 + row] = s;
            aldT[(size_t)h * N_NODES + row0 + row] = d;
        }
    }
}

// ---------------- layer-1 agg, inline alpha: wave per (node, head), XCD-bound ---

__global__ __launch_bounds__(256) void k_agg1(
        const float* __restrict__ xh1T, const float* __restrict__ alsT,
        const float* __restrict__ aldT, const int2* __restrict__ sw_pad,
        const int* __restrict__ cnt, const float* __restrict__ de,
        const float* __restrict__ bias, float* __restrict__ h1) {
    int b = blockIdx.x;
    int slot8 = b & 7;
    int h = slot8 >> 1;
    int nb = (b >> 3) * 2 + (slot8 & 1);           // 0..2499
    int node = nb * 4 + (threadIdx.x >> 6);
    int lane = threadIdx.x & 63;
    int es = lane >> 4;                            // edge slot
    int c4 = (lane & 15) * 4;                      // channel
    const float* xb   = xh1T + (size_t)h * N_NODES * HID;
    const float* alsb = alsT + (size_t)h * N_NODES;
    float deh  = de[h];
    float aldv = aldT[(size_t)h * N_NODES + node];
    const int2* sp = sw_pad + (size_t)node * CAP;
    int n = cnt[node]; if (n > CAP) n = CAP;
    float4 acc = make_float4(0.f, 0.f, 0.f, 0.f);
    float den = 0.f;
    int i = es;
    for (; i + 12 < n; i += 16) {
        int2 r0 = sp[i], r1 = sp[i + 4], r2 = sp[i + 8], r3 = sp[i + 12];
        float al0 = alsb[r0.x], al1 = alsb[r1.x], al2 = alsb[r2.x], al3 = alsb[r3.x];
        float4 x0 = *(const float4*)(xb + (size_t)r0.x * HID + c4);
        float4 x1 = *(const float4*)(xb + (size_t)r1.x * HID + c4);
        float4 x2 = *(const float4*)(xb + (size_t)r2.x * HID + c4);
        float4 x3 = *(const float4*)(xb + (size_t)r3.x * HID + c4);
        float a0 = al0 + aldv + __int_as_float(r0.y) * deh;
        float a1 = al1 + aldv + __int_as_float(r1.y) * deh;
        float a2 = al2 + aldv + __int_as_float(r2.y) * deh;
        float a3 = al3 + aldv + __int_as_float(r3.y) * deh;
        a0 = a0 > 0.f ? a0 : NEG_SLOPE * a0;
        a1 = a1 > 0.f ? a1 : NEG_SLOPE * a1;
        a2 = a2 > 0.f ? a2 : NEG_SLOPE * a2;
        a3 = a3 > 0.f ? a3 : NEG_SLOPE * a3;
        float e0 = __expf(a0), e1 = __expf(a1), e2 = __expf(a2), e3 = __expf(a3);
        den += (e0 + e1) + (e2 + e3);
        acc.x = fmaf(e0, x0.x, fmaf(e1, x1.x, fmaf(e2, x2.x, fmaf(e3, x3.x, acc.x))));
        acc.y = fmaf(e0, x0.y, fmaf(e1, x1.y, fmaf(e2, x2.y, fmaf(e3, x3.y, acc.y))));
        acc.z = fmaf(e0, x0.z, fmaf(e1, x1.z, fmaf(e2, x2.z, fmaf(e3, x3.z, acc.z))));
        acc.w = fmaf(e0, x0.w, fmaf(e1, x1.w, fmaf(e2, x2.w, fmaf(e3, x3.w, acc.w))));
    }
    for (; i < n; i += 4) {
        int2 r0 = sp[i];
        float al0 = alsb[r0.x];
        float4 x0 = *(const float4*)(xb + (size_t)r0.x * HID + c4);
        float a0 = al0 + aldv + __int_as_float(r0.y) * deh;
        a0 = a0 > 0.f ? a0 : NEG_SLOPE * a0;
        float e0 = __expf(a0);
        den += e0;
        acc.x = fmaf(e0, x0.x, acc.x);
        acc.y = fmaf(e0, x0.y, acc.y);
        acc.z = fmaf(e0, x0.z, acc.z);
        acc.w = fmaf(e0, x0.w, acc.w);
    }
    #pragma unroll
    for (int off = 32; off >= 16; off >>= 1) {
        acc.x += __shfl_xor(acc.x, off, 64);
        acc.y += __shfl_xor(acc.y, off, 64);
        acc.z += __shfl_xor(acc.z, off, 64);
        acc.w += __shfl_xor(acc.w, off, 64);
        den   += __shfl_xor(den,   off, 64);
    }
    if (es == 0) {
        float inv = 1.f / (den + 1e-16f);
        int cb = h * HID + c4;
        float4 o;
        o.x = fmaf(acc.x, inv, bias[cb + 0]);
        o.y = fmaf(acc.y, inv, bias[cb + 1]);
        o.z = fmaf(acc.z, inv, bias[cb + 2]);
        o.w = fmaf(acc.w, inv, bias[cb + 3]);
        o.x = o.x > 0.f ? o.x : expm1f(o.x);
        o.y = o.y > 0.f ? o.y : expm1f(o.y);
        o.z = o.z > 0.f ? o.z : expm1f(o.z);
        o.w = o.w > 0.f ? o.w : expm1f(o.w);
        *(float4*)(h1 + (size_t)node * F1 + cb) = o;
    }
}

// ---------------- GEMM2 + fused dots2 ----------------

__global__ __launch_bounds__(256) void k_gemm2(const float* __restrict__ hin,
                                               const float* __restrict__ W,
                                               const float* __restrict__ a_src,
                                               const float* __restrict__ a_dst,
                                               float* __restrict__ xh2,
                                               float* __restrict__ als,
                                               float* __restrict__ ald) {
    __shared__ float hs[32 * F1];
    int tid = threadIdx.x;
    int row0 = blockIdx.x * 32;
    int nrows = N_NODES - row0; if (nrows > 32) nrows = 32;
    float4* hs4 = (float4*)hs;
    const float4* hg = (const float4*)(hin + (size_t)row0 * F1);
    #pragma unroll
    for (int j = 0; j < 8; ++j) {
        int idx = tid + j * 256;
        if ((idx >> 6) < nrows) hs4[idx] = hg[idx];
    }
    __syncthreads();
    int rowg = tid >> 4;
    int col = (tid & 15) * 4;
    float acc[2][4];
    #pragma unroll
    for (int m = 0; m < 2; ++m)
        #pragma unroll
        for (int j = 0; j < 4; ++j) acc[m][j] = 0.f;
    for (int k = 0; k < F1; k += 4) {
        float4 w0 = *(const float4*)(W + (size_t)(k + 0) * OUT_CH + col);
        float4 w1 = *(const float4*)(W + (size_t)(k + 1) * OUT_CH + col);
        float4 w2 = *(const float4*)(W + (size_t)(k + 2) * OUT_CH + col);
        float4 w3 = *(const float4*)(W + (size_t)(k + 3) * OUT_CH + col);
        #pragma unroll
        for (int m = 0; m < 2; ++m) {
            float4 xv = *(const float4*)(hs + (rowg * 2 + m) * F1 + k);
            acc[m][0] = fmaf(xv.x, w0.x, fmaf(xv.y, w1.x, fmaf(xv.z, w2.x, fmaf(xv.w, w3.x, acc[m][0]))));
            acc[m][1] = fmaf(xv.x, w0.y, fmaf(xv.y, w1.y, fmaf(xv.z, w2.y, fmaf(xv.w, w3.y, acc[m][1]))));
            acc[m][2] = fmaf(xv.x, w0.z, fmaf(xv.y, w1.z, fmaf(xv.z, w2.z, fmaf(xv.w, w3.z, acc[m][2]))));
            acc[m][3] = fmaf(xv.x, w0.w, fmaf(xv.y, w1.w, fmaf(xv.z, w2.w, fmaf(xv.w, w3.w, acc[m][3]))));
        }
    }
    int lane = tid & 63;
    float4 asv = *(const float4*)(a_src + col);
    float4 adv = *(const float4*)(a_dst + col);
    #pragma unroll
    for (int m = 0; m < 2; ++m) {
        int row = rowg * 2 + m;
        if (row < nrows) *(float4*)(xh2 + (size_t)(row0 + row) * OUT_CH + col) = *(float4*)acc[m];
        float s = acc[m][0] * asv.x + acc[m][1] * asv.y + acc[m][2] * asv.z + acc[m][3] * asv.w;
        float d = acc[m][0] * adv.x + acc[m][1] * adv.y + acc[m][2] * adv.z + acc[m][3] * adv.w;
        #pragma unroll
        for (int off = 1; off < 16; off <<= 1) {
            s += __shfl_xor(s, off, 64);
            d += __shfl_xor(d, off, 64);
        }
        if ((lane & 15) == 0 && row < nrows) {
            als[row0 + row] = s;
            ald[row0 + row] = d;
        }
    }
}

// ---------------- layer-2 agg, inline alpha: wave per node ----------------

__global__ __launch_bounds__(256) void k_agg2(
        const float* __restrict__ xh2, const float* __restrict__ als,
        const float* __restrict__ ald, const int2* __restrict__ sw_pad,
        const int* __restrict__ cnt, const float* __restrict__ de,
        const float* __restrict__ bias, float* __restrict__ out) {
    int node = blockIdx.x * 4 + (threadIdx.x >> 6);
    int lane = threadIdx.x & 63;
    int es = lane >> 4;
    int c4 = (lane & 15) * 4;
    float de2  = de[HEADS];
    float aldv = ald[node];
    const int2* sp = sw_pad + (size_t)node * CAP;
    int n = cnt[node]; if (n > CAP) n = CAP;
    float4 acc = make_float4(0.f, 0.f, 0.f, 0.f);
    float den = 0.f;
    int i = es;
    for (; i + 12 < n; i += 16) {
        int2 r0 = sp[i], r1 = sp[i + 4], r2 = sp[i + 8], r3 = sp[i + 12];
        float al0 = als[r0.x], al1 = als[r1.x], al2 = als[r2.x], al3 = als[r3.x];
        float4 x0 = *(const float4*)(xh2 + (size_t)r0.x * OUT_CH + c4);
        float4 x1 = *(const float4*)(xh2 + (size_t)r1.x * OUT_CH + c4);
        float4 x2 = *(const float4*)(xh2 + (size_t)r2.x * OUT_CH + c4);
        float4 x3 = *(const float4*)(xh2 + (size_t)r3.x * OUT_CH + c4);
        float a0 = al0 + aldv + __int_as_float(r0.y) * de2;
        float a1 = al1 + aldv + __int_as_float(r1.y) * de2;
        float a2 = al2 + aldv + __int_as_float(r2.y) * de2;
        float a3 = al3 + aldv + __int_as_float(r3.y) * de2;
        a0 = a0 > 0.f ? a0 : NEG_SLOPE * a0;
        a1 = a1 > 0.f ? a1 : NEG_SLOPE * a1;
        a2 = a2 > 0.f ? a2 : NEG_SLOPE * a2;
        a3 = a3 > 0.f ? a3 : NEG_SLOPE * a3;
        float e0 = __expf(a0), e1 = __expf(a1), e2 = __expf(a2), e3 = __expf(a3);
        den += (e0 + e1) + (e2 + e3);
        acc.x = fmaf(e0, x0.x, fmaf(e1, x1.x, fmaf(e2, x2.x, fmaf(e3, x3.x, acc.x))));
        acc.y = fmaf(e0, x0.y, fmaf(e1, x1.y, fmaf(e2, x2.y, fmaf(e3, x3.y, acc.y))));
        acc.z = fmaf(e0, x0.z, fmaf(e1, x1.z, fmaf(e2, x2.z, fmaf(e3, x3.z, acc.z))));
        acc.w = fmaf(e0, x0.w, fmaf(e1, x1.w, fmaf(e3, x3.w, fmaf(e2, x2.w, acc.w))));
    }
    for (; i < n; i += 4) {
        int2 r0 = sp[i];
        float al0 = als[r0.x];
        float4 x0 = *(const float4*)(xh2 + (size_t)r0.x * OUT_CH + c4);
        float a0 = al0 + aldv + __int_as_float(r0.y) * de2;
        a0 = a0 > 0.f ? a0 : NEG_SLOPE * a0;
        float e0 = __expf(a0);
        den += e0;
        acc.x = fmaf(e0, x0.x, acc.x);
        acc.y = fmaf(e0, x0.y, acc.y);
        acc.z = fmaf(e0, x0.z, acc.z);
        acc.w = fmaf(e0, x0.w, acc.w);
    }
    #pragma unroll
    for (int off = 32; off >= 16; off >>= 1) {
        acc.x += __shfl_xor(acc.x, off, 64);
        acc.y += __shfl_xor(acc.y, off, 64);
        acc.z += __shfl_xor(acc.z, off, 64);
        acc.w += __shfl_xor(acc.w, off, 64);
        den   += __shfl_xor(den,   off, 64);
    }
    if (es == 0) {
        float inv = 1.f / (den + 1e-16f);
        float4 o;
        o.x = fmaf(acc.x, inv, bias[c4 + 0]);
        o.y = fmaf(acc.y, inv, bias[c4 + 1]);
        o.z = fmaf(acc.z, inv, bias[c4 + 2]);
        o.w = fmaf(acc.w, inv, bias[c4 + 3]);
        *(float4*)(out + (size_t)node * OUT_CH + c4) = o;
    }
}

// ---------------- launch ----------------

extern "C" void kernel_launch(void* const* d_in, const int* in_sizes, int n_in,
                              void* d_out, int out_size, void* d_ws, size_t ws_size,
                              hipStream_t stream) {
    const float* x       = (const float*)d_in[0];
    const float* ew      = (const float*)d_in[1];
    const float* W1      = (const float*)d_in[2];
    const float* a_src1  = (const float*)d_in[3];
    const float* a_dst1  = (const float*)d_in[4];
    const float* a_edge1 = (const float*)d_in[5];
    const float* We1     = (const float*)d_in[6];
    const float* b1      = (const float*)d_in[7];
    const float* W2      = (const float*)d_in[8];
    const float* a_src2  = (const float*)d_in[9];
    const float* a_dst2  = (const float*)d_in[10];
    const float* a_edge2 = (const float*)d_in[11];
    const float* We2     = (const float*)d_in[12];
    const float* b2      = (const float*)d_in[13];
    const int*   eidx    = (const int*)d_in[14];
    const int* esrc = eidx;
    const int* edst = eidx + N_EDGES;
    float* out = (float*)d_out;

    char* p = (char*)d_ws;
    auto alloc = [&](size_t bytes) {
        char* r = p;
        p += (bytes + 255) & ~(size_t)255;
        return r;
    };
    float* xh1T   = (float*)alloc((size_t)N_NODES * F1 * 4);       // head-major
    float* h1     = (float*)alloc((size_t)N_NODES * F1 * 4);
    float* xh2    = (float*)alloc((size_t)N_NODES * OUT_CH * 4);
    float* alsT   = (float*)alloc((size_t)N_NODES * HEADS * 4);    // [h][node]
    float* aldT   = (float*)alloc((size_t)N_NODES * HEADS * 4);
    float* als2   = (float*)alloc((size_t)N_NODES * 4);
    float* ald2   = (float*)alloc((size_t)N_NODES * 4);
    float* de     = (float*)alloc(8 * 4);
    int*   cnt    = (int*)alloc((size_t)N_NODES * 4);
    int2*  sw_pad = (int2*)alloc((size_t)N_NODES * CAP * 8);       // 10.24 MB

    // init: zero cnt + de
    k_init<<<41, 256, 0, stream>>>(cnt, We1, a_edge1, We2, a_edge2, de);

    // fill padded buckets (8B scatter only; independent of gemm1)
    k_fill<<<HALF_E / 256, 256, 0, stream>>>(esrc, edst, ew, cnt, sw_pad);

    // GEMM1 (+dots1, head-major)
    k_gemm1<<<GEMM_BLOCKS, 256, 0, stream>>>(x, W1, a_src1, a_dst1, xh1T, alsT, aldT);

    // layer-1 agg (inline alpha + softmax + bias + ELU)
    k_agg1<<<N_NODES / 4 * HEADS, 256, 0, stream>>>(
        xh1T, alsT, aldT, sw_pad, cnt, de, b1, h1);

    // layer 2
    k_gemm2<<<GEMM_BLOCKS, 256, 0, stream>>>(h1, W2, a_src2, a_dst2, xh2, als2, ald2);
    k_agg2<<<N_NODES / 4, 256, 0, stream>>>(xh2, als2, ald2, sw_pad, cnt, de, b2, out);
}

// Round 11
// 119.073 us; speedup vs baseline: 1.0225x; 1.0225x over previous
//
#include <hip/hip_runtime.h>

constexpr int N_NODES = 10000;
constexpr int N_EDGES = 320000;
constexpr int IN_CH   = 128;
constexpr int HID     = 64;
constexpr int HEADS   = 4;
constexpr int OUT_CH  = 64;
constexpr int F1      = HEADS * HID;   // 256
constexpr int CAP     = 128;           // max in-degree capacity (deg~Poisson(32))
constexpr float NEG_SLOPE = 0.2f;
constexpr int GEMM_BLOCKS = (N_NODES + 31) / 32;   // 313
constexpr int HALF_E = N_EDGES / 2;                // 160000
constexpr int FILL_BLOCKS = HALF_E / 256;          // 625

// ---------------- fill: padded buckets (8B scatter), 2 edges/thread; de tail ----

__global__ void k_fill(const int* __restrict__ src, const int* __restrict__ dst,
                       const float* __restrict__ ew,
                       int* __restrict__ cnt, int2* __restrict__ sw_pad,
                       const float* __restrict__ We1, const float* __restrict__ ae1,
                       const float* __restrict__ We2, const float* __restrict__ ae2,
                       float* __restrict__ de) {
    if (blockIdx.x == FILL_BLOCKS) {
        int t = threadIdx.x;
        if (t < HEADS) {
            float s = 0.f;
            for (int c = 0; c < HID; ++c) s = fmaf(We1[t * HID + c], ae1[t * HID + c], s);
            de[t] = s;
        } else if (t == HEADS) {
            float s = 0.f;
            for (int c = 0; c < OUT_CH; ++c) s = fmaf(We2[c], ae2[c], s);
            de[HEADS] = s;
        }
        return;
    }
    int e0 = blockIdx.x * 256 + threadIdx.x;   // covers [0, HALF_E)
    int e1 = e0 + HALF_E;
    int s0 = src[e0], d0 = dst[e0];
    int s1 = src[e1], d1 = dst[e1];
    float w0 = ew[e0], w1 = ew[e1];
    int p0 = atomicAdd(&cnt[d0], 1);
    int p1 = atomicAdd(&cnt[d1], 1);
    if (p0 < CAP) sw_pad[(size_t)d0 * CAP + p0] = make_int2(s0, __float_as_int(w0));
    if (p1 < CAP) sw_pad[(size_t)d1 * CAP + p1] = make_int2(s1, __float_as_int(w1));
}

// ---------------- GEMM1 + fused src/dst dots; all outputs head-major ------------

__global__ __launch_bounds__(256) void k_gemm1(const float* __restrict__ x,
                                               const float* __restrict__ W,
                                               const float* __restrict__ a_src,
                                               const float* __restrict__ a_dst,
                                               float* __restrict__ xh1T,
                                               float* __restrict__ alsT,
                                               float* __restrict__ aldT) {
    __shared__ float xs[32 * IN_CH];                       // 16 KB
    int tid = threadIdx.x;
    int row0 = blockIdx.x * 32;
    int nrows = N_NODES - row0; if (nrows > 32) nrows = 32;
    float4* xs4 = (float4*)xs;
    const float4* xg = (const float4*)(x + (size_t)row0 * IN_CH);
    #pragma unroll
    for (int j = 0; j < 4; ++j) {
        int idx = tid + j * 256;
        if ((idx >> 5) < nrows) xs4[idx] = xg[idx];
    }
    __syncthreads();
    int wv = tid >> 6;
    int lane = tid & 63;
    int col = lane * 4;
    int h = lane >> 4;
    int c = (lane & 15) * 4;
    float acc[8][4];
    #pragma unroll
    for (int m = 0; m < 8; ++m)
        #pragma unroll
        for (int j = 0; j < 4; ++j) acc[m][j] = 0.f;

    for (int k = 0; k < IN_CH; k += 4) {
        float4 w0 = *(const float4*)(W + (size_t)(k + 0) * F1 + col);
        float4 w1 = *(const float4*)(W + (size_t)(k + 1) * F1 + col);
        float4 w2 = *(const float4*)(W + (size_t)(k + 2) * F1 + col);
        float4 w3 = *(const float4*)(W + (size_t)(k + 3) * F1 + col);
        #pragma unroll
        for (int m = 0; m < 8; ++m) {
            float4 xv = *(const float4*)(xs + (wv * 8 + m) * IN_CH + k);
            acc[m][0] = fmaf(xv.x, w0.x, fmaf(xv.y, w1.x, fmaf(xv.z, w2.x, fmaf(xv.w, w3.x, acc[m][0]))));
            acc[m][1] = fmaf(xv.x, w0.y, fmaf(xv.y, w1.y, fmaf(xv.z, w2.y, fmaf(xv.w, w3.y, acc[m][1]))));
            acc[m][2] = fmaf(xv.x, w0.z, fmaf(xv.y, w1.z, fmaf(xv.z, w2.z, fmaf(xv.w, w3.z, acc[m][2]))));
            acc[m][3] = fmaf(xv.x, w0.w, fmaf(xv.y, w1.w, fmaf(xv.z, w2.w, fmaf(xv.w, w3.w, acc[m][3]))));
        }
    }
    float4 asv = *(const float4*)(a_src + h * HID + c);
    float4 adv = *(const float4*)(a_dst + h * HID + c);
    #pragma unroll
    for (int m = 0; m < 8; ++m) {
        int row = wv * 8 + m;
        if (row < nrows)
            *(float4*)(xh1T + ((size_t)h * N_NODES + row0 + row) * HID + c) = *(float4*)acc[m];
        float s = acc[m][0] * asv.x + acc[m][1] * asv.y + acc[m][2] * asv.z + acc[m][3] * asv.w;
        float d = acc[m][0] * adv.x + acc[m][1] * adv.y + acc[m][2] * adv.z + acc[m][3] * adv.w;
        #pragma unroll
        for (int off = 1; off < 16; off <<= 1) {
            s += __shfl_xor(s, off, 64);
            d += __shfl_xor(d, off, 64);
        }
        if ((lane & 15) == 0 && row < nrows) {
            alsT[(size_t)h * N_NODES + row0 + row] = s;
            aldT[(size_t)h * N_NODES + row0 + row] = d;
        }
    }
}

// ---------------- layer-1 agg, inline alpha, LDS-staged sw; XCD-bound ----------

__global__ __launch_bounds__(256) void k_agg1(
        const float* __restrict__ xh1T, const float* __restrict__ alsT,
        const float* __restrict__ aldT, const int2* __restrict__ sw_pad,
        const int* __restrict__ cnt, const float* __restrict__ de,
        const float* __restrict__ bias, float* __restrict__ h1) {
    __shared__ int2 sw_s[4 * CAP];                 // 4 KB
    int b = blockIdx.x;
    int slot8 = b & 7;
    int h = slot8 >> 1;
    int nb = (b >> 3) * 2 + (slot8 & 1);           // 0..2499
    int node0 = nb * 4;
    int tid = threadIdx.x;
    {   // coalesced staging of 4 contiguous nodes' sw rows (512 int4)
        const int4* g = (const int4*)(sw_pad + (size_t)node0 * CAP);
        int4* s4 = (int4*)sw_s;
        s4[tid]       = g[tid];
        s4[tid + 256] = g[tid + 256];
    }
    __syncthreads();
    int wv = tid >> 6;
    int node = node0 + wv;
    int lane = tid & 63;
    int es = lane >> 4;                            // edge slot
    int c4 = (lane & 15) * 4;                      // channel
    const float* xb   = xh1T + (size_t)h * N_NODES * HID;
    const float* alsb = alsT + (size_t)h * N_NODES;
    float deh  = de[h];
    float aldv = aldT[(size_t)h * N_NODES + node];
    const int2* sp = sw_s + wv * CAP;
    int n = cnt[node]; if (n > CAP) n = CAP;
    float4 acc = make_float4(0.f, 0.f, 0.f, 0.f);
    float den = 0.f;
    int i = es;
    for (; i + 12 < n; i += 16) {
        int2 r0 = sp[i], r1 = sp[i + 4], r2 = sp[i + 8], r3 = sp[i + 12];
        float al0 = alsb[r0.x], al1 = alsb[r1.x], al2 = alsb[r2.x], al3 = alsb[r3.x];
        float4 x0 = *(const float4*)(xb + (size_t)r0.x * HID + c4);
        float4 x1 = *(const float4*)(xb + (size_t)r1.x * HID + c4);
        float4 x2 = *(const float4*)(xb + (size_t)r2.x * HID + c4);
        float4 x3 = *(const float4*)(xb + (size_t)r3.x * HID + c4);
        float a0 = al0 + aldv + __int_as_float(r0.y) * deh;
        float a1 = al1 + aldv + __int_as_float(r1.y) * deh;
        float a2 = al2 + aldv + __int_as_float(r2.y) * deh;
        float a3 = al3 + aldv + __int_as_float(r3.y) * deh;
        a0 = a0 > 0.f ? a0 : NEG_SLOPE * a0;
        a1 = a1 > 0.f ? a1 : NEG_SLOPE * a1;
        a2 = a2 > 0.f ? a2 : NEG_SLOPE * a2;
        a3 = a3 > 0.f ? a3 : NEG_SLOPE * a3;
        float e0 = __expf(a0), e1 = __expf(a1), e2 = __expf(a2), e3 = __expf(a3);
        den += (e0 + e1) + (e2 + e3);
        acc.x = fmaf(e0, x0.x, fmaf(e1, x1.x, fmaf(e2, x2.x, fmaf(e3, x3.x, acc.x))));
        acc.y = fmaf(e0, x0.y, fmaf(e1, x1.y, fmaf(e2, x2.y, fmaf(e3, x3.y, acc.y))));
        acc.z = fmaf(e0, x0.z, fmaf(e1, x1.z, fmaf(e2, x2.z, fmaf(e3, x3.z, acc.z))));
        acc.w = fmaf(e0, x0.w, fmaf(e1, x1.w, fmaf(e2, x2.w, fmaf(e3, x3.w, acc.w))));
    }
    for (; i < n; i += 4) {
        int2 r0 = sp[i];
        float al0 = alsb[r0.x];
        float4 x0 = *(const float4*)(xb + (size_t)r0.x * HID + c4);
        float a0 = al0 + aldv + __int_as_float(r0.y) * deh;
        a0 = a0 > 0.f ? a0 : NEG_SLOPE * a0;
        float e0 = __expf(a0);
        den += e0;
        acc.x = fmaf(e0, x0.x, acc.x);
        acc.y = fmaf(e0, x0.y, acc.y);
        acc.z = fmaf(e0, x0.z, acc.z);
        acc.w = fmaf(e0, x0.w, acc.w);
    }
    #pragma unroll
    for (int off = 32; off >= 16; off >>= 1) {
        acc.x += __shfl_xor(acc.x, off, 64);
        acc.y += __shfl_xor(acc.y, off, 64);
        acc.z += __shfl_xor(acc.z, off, 64);
        acc.w += __shfl_xor(acc.w, off, 64);
        den   += __shfl_xor(den,   off, 64);
    }
    if (es == 0) {
        float inv = 1.f / (den + 1e-16f);
        int cb = h * HID + c4;
        float4 o;
        o.x = fmaf(acc.x, inv, bias[cb + 0]);
        o.y = fmaf(acc.y, inv, bias[cb + 1]);
        o.z = fmaf(acc.z, inv, bias[cb + 2]);
        o.w = fmaf(acc.w, inv, bias[cb + 3]);
        o.x = o.x > 0.f ? o.x : expm1f(o.x);
        o.y = o.y > 0.f ? o.y : expm1f(o.y);
        o.z = o.z > 0.f ? o.z : expm1f(o.z);
        o.w = o.w > 0.f ? o.w : expm1f(o.w);
        *(float4*)(h1 + (size_t)node * F1 + cb) = o;
    }
}

// ---------------- GEMM2 + fused dots2 ----------------

__global__ __launch_bounds__(256) void k_gemm2(const float* __restrict__ hin,
                                               const float* __restrict__ W,
                                               const float* __restrict__ a_src,
                                               const float* __restrict__ a_dst,
                                               float* __restrict__ xh2,
                                               float* __restrict__ als,
                                               float* __restrict__ ald) {
    __shared__ float hs[32 * F1];
    int tid = threadIdx.x;
    int row0 = blockIdx.x * 32;
    int nrows = N_NODES - row0; if (nrows > 32) nrows = 32;
    float4* hs4 = (float4*)hs;
    const float4* hg = (const float4*)(hin + (size_t)row0 * F1);
    #pragma unroll
    for (int j = 0; j < 8; ++j) {
        int idx = tid + j * 256;
        if ((idx >> 6) < nrows) hs4[idx] = hg[idx];
    }
    __syncthreads();
    int rowg = tid >> 4;
    int col = (tid & 15) * 4;
    float acc[2][4];
    #pragma unroll
    for (int m = 0; m < 2; ++m)
        #pragma unroll
        for (int j = 0; j < 4; ++j) acc[m][j] = 0.f;
    for (int k = 0; k < F1; k += 4) {
        float4 w0 = *(const float4*)(W + (size_t)(k + 0) * OUT_CH + col);
        float4 w1 = *(const float4*)(W + (size_t)(k + 1) * OUT_CH + col);
        float4 w2 = *(const float4*)(W + (size_t)(k + 2) * OUT_CH + col);
        float4 w3 = *(const float4*)(W + (size_t)(k + 3) * OUT_CH + col);
        #pragma unroll
        for (int m = 0; m < 2; ++m) {
            float4 xv = *(const float4*)(hs + (rowg * 2 + m) * F1 + k);
            acc[m][0] = fmaf(xv.x, w0.x, fmaf(xv.y, w1.x, fmaf(xv.z, w2.x, fmaf(xv.w, w3.x, acc[m][0]))));
            acc[m][1] = fmaf(xv.x, w0.y, fmaf(xv.y, w1.y, fmaf(xv.z, w2.y, fmaf(xv.w, w3.y, acc[m][1]))));
            acc[m][2] = fmaf(xv.x, w0.z, fmaf(xv.y, w1.z, fmaf(xv.z, w2.z, fmaf(xv.w, w3.z, acc[m][2]))));
            acc[m][3] = fmaf(xv.x, w0.w, fmaf(xv.y, w1.w, fmaf(xv.z, w2.w, fmaf(xv.w, w3.w, acc[m][3]))));
        }
    }
    int lane = tid & 63;
    float4 asv = *(const float4*)(a_src + col);
    float4 adv = *(const float4*)(a_dst + col);
    #pragma unroll
    for (int m = 0; m < 2; ++m) {
        int row = rowg * 2 + m;
        if (row < nrows) *(float4*)(xh2 + (size_t)(row0 + row) * OUT_CH + col) = *(float4*)acc[m];
        float s = acc[m][0] * asv.x + acc[m][1] * asv.y + acc[m][2] * asv.z + acc[m][3] * asv.w;
        float d = acc[m][0] * adv.x + acc[m][1] * adv.y + acc[m][2] * adv.z + acc[m][3] * adv.w;
        #pragma unroll
        for (int off = 1; off < 16; off <<= 1) {
            s += __shfl_xor(s, off, 64);
            d += __shfl_xor(d, off, 64);
        }
        if ((lane & 15) == 0 && row < nrows) {
            als[row0 + row] = s;
            ald[row0 + row] = d;
        }
    }
}

// ---------------- layer-2 agg, inline alpha, LDS-staged sw ----------------

__global__ __launch_bounds__(256) void k_agg2(
        const float* __restrict__ xh2, const float* __restrict__ als,
        const float* __restrict__ ald, const int2* __restrict__ sw_pad,
        const int* __restrict__ cnt, const float* __restrict__ de,
        const float* __restrict__ bias, float* __restrict__ out) {
    __shared__ int2 sw_s[4 * CAP];                 // 4 KB
    int node0 = blockIdx.x * 4;
    int tid = threadIdx.x;
    {
        const int4* g = (const int4*)(sw_pad + (size_t)node0 * CAP);
        int4* s4 = (int4*)sw_s;
        s4[tid]       = g[tid];
        s4[tid + 256] = g[tid + 256];
    }
    __syncthreads();
    int wv = tid >> 6;
    int node = node0 + wv;
    int lane = tid & 63;
    int es = lane >> 4;
    int c4 = (lane & 15) * 4;
    float de2  = de[HEADS];
    float aldv = ald[node];
    const int2* sp = sw_s + wv * CAP;
    int n = cnt[node]; if (n > CAP) n = CAP;
    float4 acc = make_float4(0.f, 0.f, 0.f, 0.f);
    float den = 0.f;
    int i = es;
    for (; i + 12 < n; i += 16) {
        int2 r0 = sp[i], r1 = sp[i + 4], r2 = sp[i + 8], r3 = sp[i + 12];
        float al0 = als[r0.x], al1 = als[r1.x], al2 = als[r2.x], al3 = als[r3.x];
        float4 x0 = *(const float4*)(xh2 + (size_t)r0.x * OUT_CH + c4);
        float4 x1 = *(const float4*)(xh2 + (size_t)r1.x * OUT_CH + c4);
        float4 x2 = *(const float4*)(xh2 + (size_t)r2.x * OUT_CH + c4);
        float4 x3 = *(const float4*)(xh2 + (size_t)r3.x * OUT_CH + c4);
        float a0 = al0 + aldv + __int_as_float(r0.y) * de2;
        float a1 = al1 + aldv + __int_as_float(r1.y) * de2;
        float a2 = al2 + aldv + __int_as_float(r2.y) * de2;
        float a3 = al3 + aldv + __int_as_float(r3.y) * de2;
        a0 = a0 > 0.f ? a0 : NEG_SLOPE * a0;
        a1 = a1 > 0.f ? a1 : NEG_SLOPE * a1;
        a2 = a2 > 0.f ? a2 : NEG_SLOPE * a2;
        a3 = a3 > 0.f ? a3 : NEG_SLOPE * a3;
        float e0 = __expf(a0), e1 = __expf(a1), e2 = __expf(a2), e3 = __expf(a3);
        den += (e0 + e1) + (e2 + e3);
        acc.x = fmaf(e0, x0.x, fmaf(e1, x1.x, fmaf(e2, x2.x, fmaf(e3, x3.x, acc.x))));
        acc.y = fmaf(e0, x0.y, fmaf(e1, x1.y, fmaf(e2, x2.y, fmaf(e3, x3.y, acc.y))));
        acc.z = fmaf(e0, x0.z, fmaf(e1, x1.z, fmaf(e2, x2.z, fmaf(e3, x3.z, acc.z))));
        acc.w = fmaf(e0, x0.w, fmaf(e1, x1.w, fmaf(e2, x2.w, fmaf(e3, x3.w, acc.w))));
    }
    for (; i < n; i += 4) {
        int2 r0 = sp[i];
        float al0 = als[r0.x];
        float4 x0 = *(const float4*)(xh2 + (size_t)r0.x * OUT_CH + c4);
        float a0 = al0 + aldv + __int_as_float(r0.y) * de2;
        a0 = a0 > 0.f ? a0 : NEG_SLOPE * a0;
        float e0 = __expf(a0);
        den += e0;
        acc.x = fmaf(e0, x0.x, acc.x);
        acc.y = fmaf(e0, x0.y, acc.y);
        acc.z = fmaf(e0, x0.z, acc.z);
        acc.w = fmaf(e0, x0.w, acc.w);
    }
    #pragma unroll
    for (int off = 32; off >= 16; off >>= 1) {
        acc.x += __shfl_xor(acc.x, off, 64);
        acc.y += __shfl_xor(acc.y, off, 64);
        acc.z += __shfl_xor(acc.z, off, 64);
        acc.w += __shfl_xor(acc.w, off, 64);
        den   += __shfl_xor(den,   off, 64);
    }
    if (es == 0) {
        float inv = 1.f / (den + 1e-16f);
        float4 o;
        o.x = fmaf(acc.x, inv, bias[c4 + 0]);
        o.y = fmaf(acc.y, inv, bias[c4 + 1]);
        o.z = fmaf(acc.z, inv, bias[c4 + 2]);
        o.w = fmaf(acc.w, inv, bias[c4 + 3]);
        *(float4*)(out + (size_t)node * OUT_CH + c4) = o;
    }
}

// ---------------- launch ----------------

extern "C" void kernel_launch(void* const* d_in, const int* in_sizes, int n_in,
                              void* d_out, int out_size, void* d_ws, size_t ws_size,
                              hipStream_t stream) {
    const float* x       = (const float*)d_in[0];
    const float* ew      = (const float*)d_in[1];
    const float* W1      = (const float*)d_in[2];
    const float* a_src1  = (const float*)d_in[3];
    const float* a_dst1  = (const float*)d_in[4];
    const float* a_edge1 = (const float*)d_in[5];
    const float* We1     = (const float*)d_in[6];
    const float* b1      = (const float*)d_in[7];
    const float* W2      = (const float*)d_in[8];
    const float* a_src2  = (const float*)d_in[9];
    const float* a_dst2  = (const float*)d_in[10];
    const float* a_edge2 = (const float*)d_in[11];
    const float* We2     = (const float*)d_in[12];
    const float* b2      = (const float*)d_in[13];
    const int*   eidx    = (const int*)d_in[14];
    const int* esrc = eidx;
    const int* edst = eidx + N_EDGES;
    float* out = (float*)d_out;

    char* p = (char*)d_ws;
    auto alloc = [&](size_t bytes) {
        char* r = p;
        p += (bytes + 255) & ~(size_t)255;
        return r;
    };
    float* xh1T   = (float*)alloc((size_t)N_NODES * F1 * 4);       // head-major
    float* h1     = (float*)alloc((size_t)N_NODES * F1 * 4);
    float* xh2    = (float*)alloc((size_t)N_NODES * OUT_CH * 4);
    float* alsT   = (float*)alloc((size_t)N_NODES * HEADS * 4);    // [h][node]
    float* aldT   = (float*)alloc((size_t)N_NODES * HEADS * 4);
    float* als2   = (float*)alloc((size_t)N_NODES * 4);
    float* ald2   = (float*)alloc((size_t)N_NODES * 4);
    float* de     = (float*)alloc(8 * 4);
    int*   cnt    = (int*)alloc((size_t)N_NODES * 4);
    int2*  sw_pad = (int2*)alloc((size_t)N_NODES * CAP * 8);       // 10.24 MB

    // zero cnt (blit)
    hipMemsetAsync(cnt, 0, (size_t)N_NODES * 4, stream);

    // fill padded buckets (+de tail block)
    k_fill<<<FILL_BLOCKS + 1, 256, 0, stream>>>(esrc, edst, ew, cnt, sw_pad,
                                                We1, a_edge1, We2, a_edge2, de);

    // GEMM1 (+dots1, head-major)
    k_gemm1<<<GEMM_BLOCKS, 256, 0, stream>>>(x, W1, a_src1, a_dst1, xh1T, alsT, aldT);

    // layer-1 agg (inline alpha + softmax + bias + ELU)
    k_agg1<<<N_NODES / 4 * HEADS, 256, 0, stream>>>(
        xh1T, alsT, aldT, sw_pad, cnt, de, b1, h1);

    // layer 2
    k_gemm2<<<GEMM_BLOCKS, 256, 0, stream>>>(h1, W2, a_src2, a_dst2, xh2, als2, ald2);
    k_agg2<<<N_NODES / 4, 256, 0, stream>>>(xh2, als2, ald2, sw_pad, cnt, de, b2, out);
}